// Round 3
// baseline (73.486 us; speedup 1.0000x reference)
//
#include <hip/hip_runtime.h>

#define NN 512
#define DD 128
#define MARGIN_F 0.3f
#define TS 32          // distance-matrix tile (32x32), 16x16 tile grid
#define NSLOT 16       // spread accumulator slots (contention: 32 blocks/slot)

// Chunk-XOR swizzle: float4-chunk c4 of row r lives at c4 ^ ((r>>1)&7).
// Read patterns (A: 4 rows/wave broadcast-16; B: 16 even rows, same chunk)
// land on >=8 distinct bank-groups -> <=2-way (free, m136). Padding cannot
// achieve this for b128: any multiple-of-4 pad keeps even-row strides in
// bank set {0,8,16,24} (4-way). Staging writes stay within-row permutations.
#define SW(r, c4) ((c4) ^ (((r) >> 1) & 7))

// Kernel A: distance matrix via the Gram trick, tiled 32x32, swizzled LDS.
// d[i][j] = sqrt(max(n_i + n_j - 2*x_i.x_j, 0)) — the reference's formula.
// Block 0 additionally zero-inits the fused-reduce accumulators (visible to
// kernel B via the kernel-boundary flush — same R3-verified pattern as psum).
__global__ __launch_bounds__(256) void dist_tile_kernel(
    const float* __restrict__ x,
    float* __restrict__ D,
    float* __restrict__ gsum,
    unsigned int* __restrict__ gcnt,
    unsigned int* __restrict__ ndone) {

    const int bi = blockIdx.x >> 4;    // tile row
    const int bj = blockIdx.x & 15;    // tile col
    const int t  = threadIdx.x;

    if (blockIdx.x == 0) {             // init accumulators for kernel B
        if (t < NSLOT) gsum[t] = 0.0f;
        else if (t < 2 * NSLOT) gcnt[t - NSLOT] = 0u;
        else if (t == 2 * NSLOT) *ndone = 0u;
    }

    __shared__ float4 As4[TS][32];     // 16 KB, swizzled
    __shared__ float4 Bs4[TS][32];     // 16 KB, swizzled
    __shared__ float nA[TS];
    __shared__ float nB[TS];

    const float4* xa = (const float4*)(x + bi * TS * DD);
    const float4* xb = (const float4*)(x + bj * TS * DD);

    // Stage 32x128 A/B tiles (coalesced float4) + in-register row norms.
    // Per it, each half-wave (32 lanes) covers exactly one row.
#pragma unroll
    for (int it = 0; it < 4; ++it) {
        int f = it * 256 + t;          // 0..1023 float4 index
        int r = f >> 5;
        int c4 = f & 31;
        float4 va = xa[f];
        float4 vb = xb[f];
        As4[r][SW(r, c4)] = va;
        Bs4[r][SW(r, c4)] = vb;
        float sa = va.x * va.x + va.y * va.y + va.z * va.z + va.w * va.w;
        float sb = vb.x * vb.x + vb.y * vb.y + vb.z * vb.z + vb.w * vb.w;
#pragma unroll
        for (int m = 16; m >= 1; m >>= 1) {
            sa += __shfl_xor(sa, m, 32);   // width 32: stay inside half-wave
            sb += __shfl_xor(sb, m, 32);
        }
        if ((t & 31) == 0) { nA[r] = sa; nB[r] = sb; }
    }
    __syncthreads();

    // 2x2 micro-tile per thread: rows {2ty,2ty+1}, cols {2tx,2tx+1}.
    const int ty = t >> 4;
    const int tx = t & 15;
    float acc00 = 0.f, acc01 = 0.f, acc10 = 0.f, acc11 = 0.f;
#pragma unroll
    for (int k4 = 0; k4 < 32; ++k4) {
        float4 a0 = As4[2 * ty][SW(2 * ty, k4)];
        float4 a1 = As4[2 * ty + 1][SW(2 * ty + 1, k4)];
        float4 b0 = Bs4[2 * tx][SW(2 * tx, k4)];
        float4 b1 = Bs4[2 * tx + 1][SW(2 * tx + 1, k4)];
        acc00 = fmaf(a0.x, b0.x, acc00); acc00 = fmaf(a0.y, b0.y, acc00);
        acc00 = fmaf(a0.z, b0.z, acc00); acc00 = fmaf(a0.w, b0.w, acc00);
        acc01 = fmaf(a0.x, b1.x, acc01); acc01 = fmaf(a0.y, b1.y, acc01);
        acc01 = fmaf(a0.z, b1.z, acc01); acc01 = fmaf(a0.w, b1.w, acc01);
        acc10 = fmaf(a1.x, b0.x, acc10); acc10 = fmaf(a1.y, b0.y, acc10);
        acc10 = fmaf(a1.z, b0.z, acc10); acc10 = fmaf(a1.w, b0.w, acc10);
        acc11 = fmaf(a1.x, b1.x, acc11); acc11 = fmaf(a1.y, b1.y, acc11);
        acc11 = fmaf(a1.z, b1.z, acc11); acc11 = fmaf(a1.w, b1.w, acc11);
    }

    // Epilogue: safe sqrt (sq<=0 -> 0), float2 stores (cols contiguous).
    const float n0 = nA[2 * ty], n1 = nA[2 * ty + 1];
    const float m0 = nB[2 * tx], m1 = nB[2 * tx + 1];
    float2 r0, r1;
    r0.x = sqrtf(fmaxf(n0 + m0 - 2.f * acc00, 0.f));
    r0.y = sqrtf(fmaxf(n0 + m1 - 2.f * acc01, 0.f));
    r1.x = sqrtf(fmaxf(n1 + m0 - 2.f * acc10, 0.f));
    r1.y = sqrtf(fmaxf(n1 + m1 - 2.f * acc11, 0.f));
    const int gr = bi * TS + 2 * ty;
    const int gc = bj * TS + 2 * tx;
    *(float2*)&D[gr * NN + gc] = r0;
    *(float2*)&D[(gr + 1) * NN + gc] = r1;
}

// Kernel B: triplet phase + FUSED final reduce (3 nodes -> 2 this round).
// Block i reads its precomputed D-row (2 KB, L2-hit), compacts positives,
// reduces relu(d_ij + margin - d_ik) over negatives, then atomicAdds its
// partial into one of 16 spread slots (device-scope, memory-side coherent
// point -> cross-XCD safe, NO polling — the R4 spin-cost lesson concerned
// spin-WAITING, which we don't do). A done-counter elects the last block;
// it re-reads the slots via zero-atomics (16 lanes in parallel, ~1 latency)
// and writes sum/(cnt+eps).
__global__ __launch_bounds__(512) void triplet_fused_kernel(
    const float* __restrict__ D,
    const int* __restrict__ labels,
    float* __restrict__ gsum,
    unsigned int* __restrict__ gcnt,
    unsigned int* __restrict__ ndone,
    float* __restrict__ out) {

    const int i = blockIdx.x;
    const int tid = threadIdx.x;   // one j (and one k) per thread

    __shared__ int ls[NN];
    __shared__ float tvals[NN];    // d_ij + margin for each positive j
    __shared__ int npos;
    __shared__ float wsum[8];
    __shared__ unsigned int wcnt[8];
    __shared__ int islast;

    if (tid == 0) npos = 0;
    const float dj = D[i * NN + tid];   // d_ij; also d_ik for k==tid
    ls[tid] = labels[tid];
    __syncthreads();

    const int li = ls[i];
    if (ls[tid] == li && tid != i) {
        int p = atomicAdd(&npos, 1);    // LDS atomic, ~10 per block
        tvals[p] = dj + MARGIN_F;
    }
    __syncthreads();

    // Triplet reduction: thread tid owns k == tid (dk == dj).
    const int np = npos;
    float lsum = 0.0f;
    unsigned int lcnt = 0u;
    if (ls[tid] != li) {                // negative k (excludes k==i)
        for (int p = 0; p < np; ++p) {
            float v = tvals[p] - dj;    // tvals broadcast read
            lsum += fmaxf(v, 0.0f);
            lcnt += (v > 1e-16f) ? 1u : 0u;
        }
    }

    // Wave (64) shuffle reduction, then cross-wave via LDS (8 waves).
    for (int off = 32; off > 0; off >>= 1) {
        lsum += __shfl_down(lsum, off);
        lcnt += __shfl_down(lcnt, off);
    }
    const int wave = tid >> 6;
    const int lane = tid & 63;
    if (lane == 0) { wsum[wave] = lsum; wcnt[wave] = lcnt; }
    __syncthreads();

    if (tid == 0) {
        float bs = 0.0f;
        unsigned int bc = 0u;
#pragma unroll
        for (int w = 0; w < 8; ++w) { bs += wsum[w]; bc += wcnt[w]; }
        atomicAdd(&gsum[i & (NSLOT - 1)], bs);
        atomicAdd(&gcnt[i & (NSLOT - 1)], bc);
        __threadfence();                         // adds visible before count
        unsigned int old = atomicAdd(ndone, 1u);
        islast = (old == NN - 1) ? 1 : 0;
    }
    __syncthreads();

    if (islast && tid < NSLOT) {
        // 16 lanes issue their slot-reads in parallel (atomic read = add 0).
        float s = atomicAdd(&gsum[tid], 0.0f);
        unsigned int c = atomicAdd(&gcnt[tid], 0u);
#pragma unroll
        for (int off = 8; off > 0; off >>= 1) {
            s += __shfl_down(s, off);
            c += __shfl_down(c, off);
        }
        if (tid == 0) out[0] = s / ((float)c + 1e-16f);
    }
}

extern "C" void kernel_launch(void* const* d_in, const int* in_sizes, int n_in,
                              void* d_out, int out_size, void* d_ws, size_t ws_size,
                              hipStream_t stream) {
    const float* x = (const float*)d_in[0];     // [512,128] fp32
    const int* labels = (const int*)d_in[1];    // [512] int32
    float* out = (float*)d_out;                 // scalar fp32

    float* gsum = (float*)d_ws;                                // 16 floats
    unsigned int* gcnt = (unsigned int*)((char*)d_ws + 64);    // 16 uints
    unsigned int* ndone = (unsigned int*)((char*)d_ws + 128);  // 1 uint
    float* Dm = (float*)((char*)d_ws + 4096);                  // [512][512] = 1 MB

    dist_tile_kernel<<<256, 256, 0, stream>>>(x, Dm, gsum, gcnt, ndone);
    triplet_fused_kernel<<<NN, 512, 0, stream>>>(Dm, labels, gsum, gcnt, ndone, out);
}

// Round 4
// 64.478 us; speedup vs baseline: 1.1397x; 1.1397x over previous
//
#include <hip/hip_runtime.h>

#define NN 512
#define DD 128
#define MARGIN_F 0.3f
#define TS 32          // distance-matrix tile (32x32), 16x16 tile grid

// Chunk-XOR swizzle: float4-chunk c4 of row r lives at c4 ^ ((r>>1)&7).
// B-reads (16 even rows, same chunk) -> tx and tx+8 alias -> exactly 2-way
// (free, m136); A-reads -> 4 distinct bank-groups, broadcast-16 each -> free.
// Padding cannot achieve this for b128 reads: any multiple-of-4-float pad
// keeps even-row strides in bank-group set {0,8,16,24} (4-way, 1.58x).
// Staging writes stay within-row permutations (no extra write cycles).
#define SW(r, c4) ((c4) ^ (((r) >> 1) & 7))

// Kernel A: distance matrix via the Gram trick, tiled 32x32, swizzled LDS.
// d[i][j] = sqrt(max(n_i + n_j - 2*x_i.x_j, 0)) — the reference's formula.
// R3 LESSON (verified, +10.4 us): do NOT fuse the final reduce into kernel B
// via device-scope atomics + __threadfence — 512 per-block release fences at
// the cross-XCD coherence point cost ~10 us. Kernel boundaries are the cheap
// cross-XCD fence; keep the 3-node structure.
__global__ __launch_bounds__(256) void dist_tile_kernel(
    const float* __restrict__ x,
    float* __restrict__ D) {

    const int bi = blockIdx.x >> 4;    // tile row
    const int bj = blockIdx.x & 15;    // tile col
    const int t  = threadIdx.x;

    __shared__ float4 As4[TS][32];     // 16 KB, swizzled
    __shared__ float4 Bs4[TS][32];     // 16 KB, swizzled
    __shared__ float nA[TS];
    __shared__ float nB[TS];

    const float4* xa = (const float4*)(x + bi * TS * DD);
    const float4* xb = (const float4*)(x + bj * TS * DD);

    // Stage 32x128 A/B tiles (coalesced float4) + in-register row norms.
    // Per it, each half-wave (32 lanes) covers exactly one row.
#pragma unroll
    for (int it = 0; it < 4; ++it) {
        int f = it * 256 + t;          // 0..1023 float4 index
        int r = f >> 5;
        int c4 = f & 31;
        float4 va = xa[f];
        float4 vb = xb[f];
        As4[r][SW(r, c4)] = va;
        Bs4[r][SW(r, c4)] = vb;
        float sa = va.x * va.x + va.y * va.y + va.z * va.z + va.w * va.w;
        float sb = vb.x * vb.x + vb.y * vb.y + vb.z * vb.z + vb.w * vb.w;
#pragma unroll
        for (int m = 16; m >= 1; m >>= 1) {
            sa += __shfl_xor(sa, m, 32);   // width 32: stay inside half-wave
            sb += __shfl_xor(sb, m, 32);
        }
        if ((t & 31) == 0) { nA[r] = sa; nB[r] = sb; }
    }
    __syncthreads();

    // 2x2 micro-tile per thread: rows {2ty,2ty+1}, cols {2tx,2tx+1}.
    const int ty = t >> 4;
    const int tx = t & 15;
    float acc00 = 0.f, acc01 = 0.f, acc10 = 0.f, acc11 = 0.f;
#pragma unroll
    for (int k4 = 0; k4 < 32; ++k4) {
        float4 a0 = As4[2 * ty][SW(2 * ty, k4)];
        float4 a1 = As4[2 * ty + 1][SW(2 * ty + 1, k4)];
        float4 b0 = Bs4[2 * tx][SW(2 * tx, k4)];
        float4 b1 = Bs4[2 * tx + 1][SW(2 * tx + 1, k4)];
        acc00 = fmaf(a0.x, b0.x, acc00); acc00 = fmaf(a0.y, b0.y, acc00);
        acc00 = fmaf(a0.z, b0.z, acc00); acc00 = fmaf(a0.w, b0.w, acc00);
        acc01 = fmaf(a0.x, b1.x, acc01); acc01 = fmaf(a0.y, b1.y, acc01);
        acc01 = fmaf(a0.z, b1.z, acc01); acc01 = fmaf(a0.w, b1.w, acc01);
        acc10 = fmaf(a1.x, b0.x, acc10); acc10 = fmaf(a1.y, b0.y, acc10);
        acc10 = fmaf(a1.z, b0.z, acc10); acc10 = fmaf(a1.w, b0.w, acc10);
        acc11 = fmaf(a1.x, b1.x, acc11); acc11 = fmaf(a1.y, b1.y, acc11);
        acc11 = fmaf(a1.z, b1.z, acc11); acc11 = fmaf(a1.w, b1.w, acc11);
    }

    // Epilogue: safe sqrt (sq<=0 -> 0), float2 stores (cols contiguous).
    const float n0 = nA[2 * ty], n1 = nA[2 * ty + 1];
    const float m0 = nB[2 * tx], m1 = nB[2 * tx + 1];
    float2 r0, r1;
    r0.x = sqrtf(fmaxf(n0 + m0 - 2.f * acc00, 0.f));
    r0.y = sqrtf(fmaxf(n0 + m1 - 2.f * acc01, 0.f));
    r1.x = sqrtf(fmaxf(n1 + m0 - 2.f * acc10, 0.f));
    r1.y = sqrtf(fmaxf(n1 + m1 - 2.f * acc11, 0.f));
    const int gr = bi * TS + 2 * ty;
    const int gc = bj * TS + 2 * tx;
    *(float2*)&D[gr * NN + gc] = r0;
    *(float2*)&D[(gr + 1) * NN + gc] = r1;
}

// Kernel B: triplet phase. Block i reads its precomputed D-row (2 KB,
// coalesced, L2-hit), compacts positives into an LDS list, reduces
// relu(d_ij + margin - d_ik) over negatives k, writes one (sum,cnt)
// partial per block. Unconditional plain stores -> no ws init needed.
__global__ __launch_bounds__(512) void triplet_partial_kernel(
    const float* __restrict__ D,
    const int* __restrict__ labels,
    float* __restrict__ psum,
    unsigned int* __restrict__ pcnt) {

    const int i = blockIdx.x;
    const int tid = threadIdx.x;   // one j (and one k) per thread

    __shared__ int ls[NN];
    __shared__ float tvals[NN];    // d_ij + margin for each positive j
    __shared__ int npos;
    __shared__ float wsum[8];
    __shared__ unsigned int wcnt[8];

    if (tid == 0) npos = 0;
    const float dj = D[i * NN + tid];   // d_ij; also d_ik for k==tid
    ls[tid] = labels[tid];
    __syncthreads();

    const int li = ls[i];
    if (ls[tid] == li && tid != i) {
        int p = atomicAdd(&npos, 1);    // LDS atomic, ~10 per block
        tvals[p] = dj + MARGIN_F;
    }
    __syncthreads();

    // Triplet reduction: thread tid owns k == tid (dk == dj).
    const int np = npos;
    float lsum = 0.0f;
    unsigned int lcnt = 0u;
    if (ls[tid] != li) {                // negative k (excludes k==i)
        for (int p = 0; p < np; ++p) {
            float v = tvals[p] - dj;    // tvals broadcast read
            lsum += fmaxf(v, 0.0f);
            lcnt += (v > 1e-16f) ? 1u : 0u;
        }
    }

    // Wave (64) shuffle reduction, then cross-wave via LDS (8 waves).
    for (int off = 32; off > 0; off >>= 1) {
        lsum += __shfl_down(lsum, off);
        lcnt += __shfl_down(lcnt, off);
    }
    const int wave = tid >> 6;
    const int lane = tid & 63;
    if (lane == 0) { wsum[wave] = lsum; wcnt[wave] = lcnt; }
    __syncthreads();

    if (tid == 0) {
        float bs = 0.0f;
        unsigned int bc = 0u;
#pragma unroll
        for (int w = 0; w < 8; ++w) { bs += wsum[w]; bc += wcnt[w]; }
        psum[i] = bs;                   // plain stores, slot per block
        pcnt[i] = bc;
    }
}

// Kernel C: reduce 512 partials -> scalar. ONE wave (64 threads): no LDS,
// no __syncthreads, serial 8-partial accumulate + shuffle tree. Kernel
// boundary gives cross-XCD visibility of kernel-B stores (R3 verified).
__global__ __launch_bounds__(64) void reduce_kernel(
    const float* __restrict__ psum,
    const unsigned int* __restrict__ pcnt,
    float* __restrict__ out) {

    const int tid = threadIdx.x;
    float lsum = 0.0f;
    unsigned int lcnt = 0u;
#pragma unroll
    for (int w = 0; w < NN / 64; ++w) {
        lsum += psum[w * 64 + tid];
        lcnt += pcnt[w * 64 + tid];
    }
    for (int off = 32; off > 0; off >>= 1) {
        lsum += __shfl_down(lsum, off);
        lcnt += __shfl_down(lcnt, off);
    }
    if (tid == 0) out[0] = lsum / ((float)lcnt + 1e-16f);
}

extern "C" void kernel_launch(void* const* d_in, const int* in_sizes, int n_in,
                              void* d_out, int out_size, void* d_ws, size_t ws_size,
                              hipStream_t stream) {
    const float* x = (const float*)d_in[0];     // [512,128] fp32
    const int* labels = (const int*)d_in[1];    // [512] int32
    float* out = (float*)d_out;                 // scalar fp32

    float* psum = (float*)d_ws;                               // 512 floats
    unsigned int* pcnt = (unsigned int*)((char*)d_ws + 2048); // 512 uints
    float* Dm = (float*)((char*)d_ws + 4096);                 // [512][512] = 1 MB

    dist_tile_kernel<<<256, 256, 0, stream>>>(x, Dm);
    triplet_partial_kernel<<<NN, 512, 0, stream>>>(Dm, labels, psum, pcnt);
    reduce_kernel<<<1, 64, 0, stream>>>(psum, pcnt, out);
}